// Round 1
// baseline (5844.567 us; speedup 1.0000x reference)
//
#include <hip/hip_runtime.h>
#include <hip/hip_bf16.h>

#define E_N 300000
#define T_N 1500000
#define CAP 32   // triplet slots per edge; Poisson(mean 5) => P(overflow) ~ 1e-12

// ---- workspace layout (bytes); all offsets 16B-aligned ----
#define O_XKJ   ((size_t)0)
#define O_XJI   (O_XKJ + (size_t)E_N * 128 * 4)       // 153,600,000
#define O_SBFB  (O_XJI + (size_t)E_N * 128 * 4)       // 307,200,000
#define O_WTBIL (O_SBFB + (size_t)T_N * 8 * 4)        // 355,200,000
#define O_WTCAT (O_WTBIL + (size_t)1024 * 128 * 4)
#define O_WTLIN (O_WTCAT + (size_t)128 * 256 * 4)
#define O_CNT   (O_WTLIN + (size_t)128 * 128 * 4)
#define O_TAB   (O_CNT + (size_t)E_N * 4)             // end ~395.5 MB

__device__ __forceinline__ float silu_f(float v) {
    return v / (1.0f + __expf(-v));
}

// ---- K0: weight transposes into [k][out] layouts ----
__global__ void k_transpose(const float* __restrict__ Wbil, const float* __restrict__ Wji,
                            const float* __restrict__ Wkj, const float* __restrict__ Wlin,
                            float* __restrict__ wtbil, float* __restrict__ wtcat,
                            float* __restrict__ wtlin) {
    int idx = blockIdx.x * 256 + threadIdx.x;
    if (idx < 1024 * 128) {                 // wtbil[k][i] = W_bil[i][k], k = j*128+l
        int i = idx & 127, k = idx >> 7;
        wtbil[idx] = Wbil[i * 1024 + k];
    }
    if (idx < 128 * 256) {                  // wtcat[c][o]: o<128 -> W_ji[o][c], else W_kj[o-128][c]
        int o = idx & 255, c = idx >> 8;
        wtcat[idx] = (o < 128) ? Wji[o * 128 + c] : Wkj[(o - 128) * 128 + c];
    }
    if (idx < 128 * 128) {                  // wtlin[c][o] = W_lin[o][c]
        int o = idx & 127, c = idx >> 7;
        wtlin[idx] = Wlin[o * 128 + c];
    }
}

// ---- K3: per-edge triplet table (counts zeroed by hipMemsetAsync before this) ----
__global__ void k_build(const int* __restrict__ idx_ji, int* __restrict__ counts,
                        int* __restrict__ table) {
    int w = blockIdx.x * 256 + threadIdx.x;
    if (w < T_N) {
        int e = idx_ji[w];
        int pos = atomicAdd(&counts[e], 1);
        if (pos < CAP) table[e * CAP + pos] = w;
    }
}

// ---- K1: sbf_b = sbf @ W_sbf.T  ([T,42] @ [42,8]) ----
__global__ __launch_bounds__(256) void k_sbfb(const float* __restrict__ sbf,
                                              const float* __restrict__ Wsbf,
                                              float* __restrict__ sbfb) {
    __shared__ float s_s[256 * 43];   // +1 pad: stride 43 coprime with 32 banks
    __shared__ float s_w[8 * 42];
    int tid = threadIdx.x;
    size_t t0 = (size_t)blockIdx.x * 256;
    int valid = T_N - (int)t0;
    if (valid > 256) valid = 256;
    for (int i = tid; i < 8 * 42; i += 256) s_w[i] = Wsbf[i];
    int tot = valid * 42;
    const float* src = sbf + t0 * 42;
    for (int i = tid; i < tot; i += 256) {   // coalesced stage of 256 rows
        int r = i / 42;
        int c = i - r * 42;
        s_s[r * 43 + c] = src[i];
    }
    __syncthreads();
    if (tid < valid) {
        float acc[8];
#pragma unroll
        for (int j = 0; j < 8; ++j) acc[j] = 0.f;
#pragma unroll 6
        for (int r = 0; r < 42; ++r) {
            float xv = s_s[tid * 43 + r];
#pragma unroll
            for (int j = 0; j < 8; ++j) acc[j] += xv * s_w[j * 42 + r];
        }
        float4* dst = (float4*)(sbfb + (t0 + tid) * 8);
        dst[0] = make_float4(acc[0], acc[1], acc[2], acc[3]);
        dst[1] = make_float4(acc[4], acc[5], acc[6], acc[7]);
    }
}

// ---- K2: fused edge linears: x_ji = silu(xW_ji^T+b), x_kj = silu(xW_kj^T+b)*rbf_h ----
// [E,128] @ [128,256] tiled GEMM; 32 edges/block; thread tile 4m x 8o (o strided by 32).
__global__ __launch_bounds__(256) void k_edges(const float* __restrict__ x,
                                               const float* __restrict__ rbf,
                                               const float* __restrict__ wtcat,
                                               const float* __restrict__ Wrbf,
                                               const float* __restrict__ bkj,
                                               const float* __restrict__ bji,
                                               float* __restrict__ xkj,
                                               float* __restrict__ xji) {
    __shared__ float s_x[32 * 128];   // 16KB
    __shared__ float s_w[16 * 256];   // 16KB k-tile of wtcat
    int tid = threadIdx.x;
    int e0 = blockIdx.x * 32;
    for (int i = tid; i < 32 * 128; i += 256) s_x[i] = x[(size_t)e0 * 128 + i];
    float acc[4][8];
#pragma unroll
    for (int a = 0; a < 4; ++a)
#pragma unroll
        for (int q = 0; q < 8; ++q) acc[a][q] = 0.f;
    int mg = tid >> 5;   // 0..7 ; m = mg + 8a
    int oc = tid & 31;   // o = oc + 32q
    for (int kt = 0; kt < 8; ++kt) {
        __syncthreads();
        for (int i = tid; i < 16 * 256; i += 256) s_w[i] = wtcat[kt * 4096 + i];
        __syncthreads();
#pragma unroll
        for (int u = 0; u < 4; ++u) {
            float4 xa[4];
#pragma unroll
            for (int a = 0; a < 4; ++a)
                xa[a] = *(const float4*)&s_x[(mg + 8 * a) * 128 + kt * 16 + u * 4];
#pragma unroll
            for (int c = 0; c < 4; ++c) {
                int kl = u * 4 + c;
                float wv[8];
#pragma unroll
                for (int q = 0; q < 8; ++q) wv[q] = s_w[kl * 256 + oc + 32 * q];
#pragma unroll
                for (int a = 0; a < 4; ++a) {
                    float xs = (c == 0) ? xa[a].x : (c == 1) ? xa[a].y : (c == 2) ? xa[a].z : xa[a].w;
#pragma unroll
                    for (int q = 0; q < 8; ++q) acc[a][q] += xs * wv[q];
                }
            }
        }
    }
#pragma unroll
    for (int a = 0; a < 4; ++a) {
        int e = e0 + mg + 8 * a;
        float r0 = rbf[e * 6 + 0], r1 = rbf[e * 6 + 1], r2 = rbf[e * 6 + 2];
        float r3 = rbf[e * 6 + 3], r4 = rbf[e * 6 + 4], r5 = rbf[e * 6 + 5];
#pragma unroll
        for (int q = 0; q < 8; ++q) {
            int o = oc + 32 * q;
            if (q < 4) {
                float v = acc[a][q] + bji[o];
                xji[(size_t)e * 128 + o] = silu_f(v);
            } else {
                int col = o - 128;
                float v = silu_f(acc[a][q] + bkj[col]);
                float rh = r0 * Wrbf[col * 6 + 0] + r1 * Wrbf[col * 6 + 1] + r2 * Wrbf[col * 6 + 2]
                         + r3 * Wrbf[col * 6 + 3] + r4 * Wrbf[col * 6 + 4] + r5 * Wrbf[col * 6 + 5];
                xkj[(size_t)e * 128 + col] = v * rh;
            }
        }
    }
}

// ---- K4: fused  P-build -> agg GEMM -> +x_ji -> final linear -> silu ----
// 16 edges/block, 256 threads, 77.9KB LDS, 2 blocks/CU.
__global__ __launch_bounds__(256, 2) void k_fused(
        const int* __restrict__ idx_kj,
        const float* __restrict__ xkj, const float* __restrict__ xji,
        const float* __restrict__ sbfb,
        const int* __restrict__ counts, const int* __restrict__ table,
        const float* __restrict__ wtbil, const float* __restrict__ wtlin,
        const float* __restrict__ blin,
        float* __restrict__ hout) {
    __shared__ float sP[16 * 1024];   // 64KB: P[m][k], k=j*128+l; reused as y[16][128] in phase 3
    __shared__ float s_wt[16 * 128];  // 8KB weight k-tile
    __shared__ int s_cnt[16];
    __shared__ int s_row[16 * CAP];
    __shared__ int s_wid[16 * CAP];
    int tid = threadIdx.x;
    int e0 = blockIdx.x * 16;

    if (tid < 16) {
        int c = counts[e0 + tid];
        s_cnt[tid] = (c > CAP) ? CAP : c;
    }
    __syncthreads();
    // phase 1a: stage triplet metadata, one slot per thread-iter (parallel latency chains)
    for (int s = tid; s < 16 * CAP; s += 256) {
        int m = s >> 5, it = s & 31;
        if (it < s_cnt[m]) {
            int w = table[(e0 + m) * CAP + it];
            s_wid[s] = w;
            s_row[s] = idx_kj[w];
        }
    }
    __syncthreads();

    // phase 1b: P accumulation in registers. thread owns l = tid&127, j = j0+2c (c=0..3)
    int l = tid & 127;
    int j0 = tid >> 7;
    int cnt_r[16];
    int maxc = 0;
#pragma unroll
    for (int m = 0; m < 16; ++m) {
        cnt_r[m] = s_cnt[m];
        maxc = max(maxc, cnt_r[m]);
    }
    float4 acc16[16];
#pragma unroll
    for (int m = 0; m < 16; ++m) acc16[m] = make_float4(0.f, 0.f, 0.f, 0.f);
    for (int it = 0; it < maxc; ++it) {
#pragma unroll
        for (int m = 0; m < 16; ++m) {
            if (it < cnt_r[m]) {
                int rw = s_row[m * CAP + it];
                int w = s_wid[m * CAP + it];
                float xv = xkj[(size_t)rw * 128 + l];
                const float4* sp = (const float4*)(sbfb + (size_t)w * 8);
                float4 sa = sp[0], sb = sp[1];
                float s0 = j0 ? sa.y : sa.x;
                float s1 = j0 ? sa.w : sa.z;
                float s2 = j0 ? sb.y : sb.x;
                float s3 = j0 ? sb.w : sb.z;
                acc16[m].x += s0 * xv;
                acc16[m].y += s1 * xv;
                acc16[m].z += s2 * xv;
                acc16[m].w += s3 * xv;
            }
        }
    }
#pragma unroll
    for (int m = 0; m < 16; ++m) {   // k = (j0+2c)*128 + l = j0*128 + 256c + l
        int base = m * 1024 + j0 * 128 + l;
        sP[base] = acc16[m].x;
        sP[base + 256] = acc16[m].y;
        sP[base + 512] = acc16[m].z;
        sP[base + 768] = acc16[m].w;
    }

    // phase 2: agg[m][i] = sum_k P[m][k] * wtbil[k][i]; thread tile 2m x 4i
    int mg = tid >> 5;   // 0..7 ; rows mg and mg+8
    int i4 = tid & 31;   // i = i4*4 .. +3
    float4 o0 = make_float4(0.f, 0.f, 0.f, 0.f), o1 = make_float4(0.f, 0.f, 0.f, 0.f);
    for (int kt = 0; kt < 64; ++kt) {
        __syncthreads();
        for (int i = tid; i < 2048; i += 256) s_wt[i] = wtbil[kt * 2048 + i];
        __syncthreads();
#pragma unroll
        for (int u = 0; u < 4; ++u) {
            float4 pa = *(const float4*)&sP[mg * 1024 + kt * 16 + u * 4];
            float4 pb = *(const float4*)&sP[(mg + 8) * 1024 + kt * 16 + u * 4];
#pragma unroll
            for (int c = 0; c < 4; ++c) {
                float4 wv = *(const float4*)&s_wt[(u * 4 + c) * 128 + i4 * 4];
                float pac = (c == 0) ? pa.x : (c == 1) ? pa.y : (c == 2) ? pa.z : pa.w;
                float pbc = (c == 0) ? pb.x : (c == 1) ? pb.y : (c == 2) ? pb.z : pb.w;
                o0.x += pac * wv.x; o0.y += pac * wv.y; o0.z += pac * wv.z; o0.w += pac * wv.w;
                o1.x += pbc * wv.x; o1.y += pbc * wv.y; o1.z += pbc * wv.z; o1.w += pbc * wv.w;
            }
        }
    }
    __syncthreads();   // all sP(P) reads done; safe to overwrite as y

    // y = x_ji + agg  into sP[0..2047]
    {
        float4 xa = *(const float4*)&xji[(size_t)(e0 + mg) * 128 + i4 * 4];
        float4 xb = *(const float4*)&xji[(size_t)(e0 + mg + 8) * 128 + i4 * 4];
        o0.x += xa.x; o0.y += xa.y; o0.z += xa.z; o0.w += xa.w;
        o1.x += xb.x; o1.y += xb.y; o1.z += xb.z; o1.w += xb.w;
        *(float4*)&sP[mg * 128 + i4 * 4] = o0;
        *(float4*)&sP[(mg + 8) * 128 + i4 * 4] = o1;
    }

    // phase 3: h = silu(y @ W_lin^T + b_lin)
    float4 h0 = make_float4(0.f, 0.f, 0.f, 0.f), h1 = make_float4(0.f, 0.f, 0.f, 0.f);
    for (int kt = 0; kt < 8; ++kt) {
        __syncthreads();
        for (int i = tid; i < 2048; i += 256) s_wt[i] = wtlin[kt * 2048 + i];
        __syncthreads();
#pragma unroll
        for (int u = 0; u < 4; ++u) {
            float4 ya = *(const float4*)&sP[mg * 128 + kt * 16 + u * 4];
            float4 yb = *(const float4*)&sP[(mg + 8) * 128 + kt * 16 + u * 4];
#pragma unroll
            for (int c = 0; c < 4; ++c) {
                float4 wv = *(const float4*)&s_wt[(u * 4 + c) * 128 + i4 * 4];
                float yac = (c == 0) ? ya.x : (c == 1) ? ya.y : (c == 2) ? ya.z : ya.w;
                float ybc = (c == 0) ? yb.x : (c == 1) ? yb.y : (c == 2) ? yb.z : yb.w;
                h0.x += yac * wv.x; h0.y += yac * wv.y; h0.z += yac * wv.z; h0.w += yac * wv.w;
                h1.x += ybc * wv.x; h1.y += ybc * wv.y; h1.z += ybc * wv.z; h1.w += ybc * wv.w;
            }
        }
    }
    float4 bl = *(const float4*)&blin[i4 * 4];
    h0.x = silu_f(h0.x + bl.x); h0.y = silu_f(h0.y + bl.y);
    h0.z = silu_f(h0.z + bl.z); h0.w = silu_f(h0.w + bl.w);
    h1.x = silu_f(h1.x + bl.x); h1.y = silu_f(h1.y + bl.y);
    h1.z = silu_f(h1.z + bl.z); h1.w = silu_f(h1.w + bl.w);
    *(float4*)&hout[(size_t)(e0 + mg) * 128 + i4 * 4] = h0;
    *(float4*)&hout[(size_t)(e0 + mg + 8) * 128 + i4 * 4] = h1;
}

extern "C" void kernel_launch(void* const* d_in, const int* in_sizes, int n_in,
                              void* d_out, int out_size, void* d_ws, size_t ws_size,
                              hipStream_t stream) {
    const float* x = (const float*)d_in[0];
    const float* rbf = (const float*)d_in[1];
    const float* sbf = (const float*)d_in[2];
    const int* idx_kj = (const int*)d_in[3];
    const int* idx_ji = (const int*)d_in[4];
    const float* Wrbf = (const float*)d_in[5];
    const float* Wsbf = (const float*)d_in[6];
    const float* Wkj = (const float*)d_in[7];
    const float* bkj = (const float*)d_in[8];
    const float* Wji = (const float*)d_in[9];
    const float* bji = (const float*)d_in[10];
    const float* Wbil = (const float*)d_in[11];
    const float* Wlin = (const float*)d_in[12];
    const float* blin = (const float*)d_in[13];
    float* hout = (float*)d_out;

    char* ws = (char*)d_ws;
    float* xkj = (float*)(ws + O_XKJ);
    float* xji = (float*)(ws + O_XJI);
    float* sbfb = (float*)(ws + O_SBFB);
    float* wtbil = (float*)(ws + O_WTBIL);
    float* wtcat = (float*)(ws + O_WTCAT);
    float* wtlin = (float*)(ws + O_WTLIN);
    int* cnts = (int*)(ws + O_CNT);
    int* tab = (int*)(ws + O_TAB);

    hipMemsetAsync(cnts, 0, (size_t)E_N * 4, stream);
    k_transpose<<<512, 256, 0, stream>>>(Wbil, Wji, Wkj, Wlin, wtbil, wtcat, wtlin);
    k_build<<<(T_N + 255) / 256, 256, 0, stream>>>(idx_ji, cnts, tab);
    k_sbfb<<<(T_N + 255) / 256, 256, 0, stream>>>(sbf, Wsbf, sbfb);
    k_edges<<<E_N / 32, 256, 0, stream>>>(x, rbf, wtcat, Wrbf, bkj, bji, xkj, xji);
    k_fused<<<E_N / 16, 256, 0, stream>>>(idx_kj, xkj, xji, sbfb, cnts, tab, wtbil, wtlin, blin, hout);
}

// Round 2
// 2903.451 us; speedup vs baseline: 2.0130x; 2.0130x over previous
//
#include <hip/hip_runtime.h>
#include <hip/hip_bf16.h>

#define E_N 300000
#define T_N 1500000
#define CAP 32   // triplet slots per edge; Poisson(mean 5) => P(overflow) ~ 1e-12

typedef __attribute__((ext_vector_type(8))) short bf16x8;
typedef __attribute__((ext_vector_type(4))) float f32x4;
#define MFMA(a, b, c) __builtin_amdgcn_mfma_f32_16x16x32_bf16((a), (b), (c), 0, 0, 0)

// ---- workspace layout (bytes); all offsets 16B-aligned ----
#define O_XKJ   ((size_t)0)
#define O_XJI   (O_XKJ + (size_t)E_N * 128 * 4)
#define O_SBFB  (O_XJI + (size_t)E_N * 128 * 4)
#define O_WBH   (O_SBFB + (size_t)T_N * 8 * 4)     // phase2 B hi: 8it*32s*64lane*8e bf16 = 256KB
#define O_WBL   (O_WBH + 262144)
#define O_WCH   (O_WBL + 262144)                   // k_edges B hi: 16ot*4s*64*8 = 64KB
#define O_WCL   (O_WCH + 65536)
#define O_WLH   (O_WCL + 65536)                    // phase3 B hi: 8ot*4s*64*8 = 32KB
#define O_WLL   (O_WLH + 32768)
#define O_CNT   (O_WLL + 32768)
#define O_TAB   (O_CNT + (size_t)E_N * 4)          // end ~395.5 MB (same footprint as r1)

__device__ __forceinline__ float silu_f(float v) {
    return v / (1.0f + __expf(-v));
}

// split fp32 -> bf16 hi (truncate) + bf16 lo (residual, truncate). err <= 2^-16 rel.
__device__ __forceinline__ void split_bf16(float v, unsigned short& h, unsigned short& l) {
    unsigned int u = __float_as_uint(v);
    h = (unsigned short)(u >> 16);
    float vh = __uint_as_float(u & 0xffff0000u);
    l = (unsigned short)(__float_as_uint(v - vh) >> 16);
}

// ---- K0: pack all GEMM weights in MFMA B-fragment order, split hi/lo bf16 ----
// B-frag layout (16x16x32): lane provides B[k = (lane>>4)*8 + e][col = lane&15],
// element index e contiguous. idx = ((tile*NS + s)*64 + lane)*8 + e.
__global__ void k_transpose(const float* __restrict__ Wbil, const float* __restrict__ Wji,
                            const float* __restrict__ Wkj, const float* __restrict__ Wlin,
                            unsigned short* __restrict__ wbh, unsigned short* __restrict__ wbl,
                            unsigned short* __restrict__ wch, unsigned short* __restrict__ wcl,
                            unsigned short* __restrict__ wlh, unsigned short* __restrict__ wll) {
    int idx = blockIdx.x * 256 + threadIdx.x;   // 512*256 = 131072 exactly covers wbil
    {
        int e = idx & 7, ln = (idx >> 3) & 63, s = (idx >> 9) & 31, it = idx >> 14;
        int k = s * 32 + ((ln >> 4) << 3) + e;      // 0..1023 (= j*128+l)
        int i = it * 16 + (ln & 15);                // 0..127
        float w = Wbil[i * 1024 + k];
        split_bf16(w, wbh[idx], wbl[idx]);
    }
    if (idx < 32768) {
        int e = idx & 7, ln = (idx >> 3) & 63, s = (idx >> 9) & 3, ot = idx >> 11;
        int k = s * 32 + ((ln >> 4) << 3) + e;      // 0..127
        int o = ot * 16 + (ln & 15);                // 0..255
        float w = (o < 128) ? Wji[o * 128 + k] : Wkj[(o - 128) * 128 + k];
        split_bf16(w, wch[idx], wcl[idx]);
    }
    if (idx < 16384) {
        int e = idx & 7, ln = (idx >> 3) & 63, s = (idx >> 9) & 3, ot = (idx >> 11) & 7;
        int k = s * 32 + ((ln >> 4) << 3) + e;
        int o = ot * 16 + (ln & 15);
        float w = Wlin[o * 128 + k];
        split_bf16(w, wlh[idx], wll[idx]);
    }
}

// ---- K3: per-edge triplet table (counts zeroed by hipMemsetAsync before this) ----
__global__ void k_build(const int* __restrict__ idx_ji, int* __restrict__ counts,
                        int* __restrict__ table) {
    int w = blockIdx.x * 256 + threadIdx.x;
    if (w < T_N) {
        int e = idx_ji[w];
        int pos = atomicAdd(&counts[e], 1);
        if (pos < CAP) table[e * CAP + pos] = w;
    }
}

// ---- K1: sbf_b = sbf @ W_sbf.T  ([T,42] @ [42,8]) ----
__global__ __launch_bounds__(256) void k_sbfb(const float* __restrict__ sbf,
                                              const float* __restrict__ Wsbf,
                                              float* __restrict__ sbfb) {
    __shared__ float s_s[256 * 43];
    __shared__ float s_w[8 * 42];
    int tid = threadIdx.x;
    size_t t0 = (size_t)blockIdx.x * 256;
    int valid = T_N - (int)t0;
    if (valid > 256) valid = 256;
    for (int i = tid; i < 8 * 42; i += 256) s_w[i] = Wsbf[i];
    int tot = valid * 42;
    const float* src = sbf + t0 * 42;
    for (int i = tid; i < tot; i += 256) {
        int r = i / 42;
        int c = i - r * 42;
        s_s[r * 43 + c] = src[i];
    }
    __syncthreads();
    if (tid < valid) {
        float acc[8];
#pragma unroll
        for (int j = 0; j < 8; ++j) acc[j] = 0.f;
#pragma unroll 6
        for (int r = 0; r < 42; ++r) {
            float xv = s_s[tid * 43 + r];
#pragma unroll
            for (int j = 0; j < 8; ++j) acc[j] += xv * s_w[j * 42 + r];
        }
        float4* dst = (float4*)(sbfb + (t0 + tid) * 8);
        dst[0] = make_float4(acc[0], acc[1], acc[2], acc[3]);
        dst[1] = make_float4(acc[4], acc[5], acc[6], acc[7]);
    }
}

// ---- K2: fused edge linears via split-bf16 MFMA ----
// [32e,128k] @ [128k,256o]; 4 waves; wave w owns o-tiles 4w..4w+3; A-frags from global x.
__global__ __launch_bounds__(256, 2) void k_edges(const float* __restrict__ x,
                                                  const float* __restrict__ rbf,
                                                  const unsigned short* __restrict__ wch,
                                                  const unsigned short* __restrict__ wcl,
                                                  const float* __restrict__ Wrbf,
                                                  const float* __restrict__ bkj,
                                                  const float* __restrict__ bji,
                                                  float* __restrict__ xkj,
                                                  float* __restrict__ xji) {
    __shared__ float s_rbf[32 * 6];
    int tid = threadIdx.x;
    int lane = tid & 63, wv = tid >> 6, lane15 = lane & 15, laneh = lane >> 4;
    int e0 = blockIdx.x * 32;
    if (tid < 192) s_rbf[tid] = rbf[e0 * 6 + tid];
    __syncthreads();
    const bf16x8* WH = (const bf16x8*)wch;
    const bf16x8* WL = (const bf16x8*)wcl;
    f32x4 acc[2][4];
#pragma unroll
    for (int mt = 0; mt < 2; ++mt)
#pragma unroll
        for (int o = 0; o < 4; ++o) acc[mt][o] = (f32x4){0.f, 0.f, 0.f, 0.f};
#pragma unroll
    for (int s = 0; s < 4; ++s) {
        bf16x8 Ah[2], Al[2];
#pragma unroll
        for (int mt = 0; mt < 2; ++mt) {
            const float* px = &x[(size_t)(e0 + mt * 16 + lane15) * 128 + s * 32 + laneh * 8];
            float4 v0 = *(const float4*)px;
            float4 v1 = *(const float4*)(px + 4);
            float vv[8] = {v0.x, v0.y, v0.z, v0.w, v1.x, v1.y, v1.z, v1.w};
            union { bf16x8 v; unsigned short u[8]; } th, tl;
#pragma unroll
            for (int e = 0; e < 8; ++e) split_bf16(vv[e], th.u[e], tl.u[e]);
            Ah[mt] = th.v;
            Al[mt] = tl.v;
        }
#pragma unroll
        for (int oti = 0; oti < 4; ++oti) {
            int bi = ((4 * wv + oti) * 4 + s) * 64 + lane;
            bf16x8 bh = WH[bi], bl = WL[bi];
#pragma unroll
            for (int mt = 0; mt < 2; ++mt) {
                acc[mt][oti] = MFMA(Ah[mt], bh, acc[mt][oti]);
                acc[mt][oti] = MFMA(Al[mt], bh, acc[mt][oti]);
                acc[mt][oti] = MFMA(Ah[mt], bl, acc[mt][oti]);
            }
        }
    }
    // epilogue: C/D layout col=lane&15, row=(lane>>4)*4+r
    float bias[4], wr[4][6];
#pragma unroll
    for (int oti = 0; oti < 4; ++oti) {
        int o = (4 * wv + oti) * 16 + lane15;
        if (wv < 2) {
            bias[oti] = bji[o];
        } else {
            bias[oti] = bkj[o - 128];
#pragma unroll
            for (int q = 0; q < 6; ++q) wr[oti][q] = Wrbf[(o - 128) * 6 + q];
        }
    }
#pragma unroll
    for (int mt = 0; mt < 2; ++mt)
#pragma unroll
        for (int r = 0; r < 4; ++r) {
            int erow = mt * 16 + laneh * 4 + r;
            float rb[6];
            if (wv >= 2) {
#pragma unroll
                for (int q = 0; q < 6; ++q) rb[q] = s_rbf[erow * 6 + q];
            }
            size_t eg = (size_t)(e0 + erow);
#pragma unroll
            for (int oti = 0; oti < 4; ++oti) {
                float v = acc[mt][oti][r] + bias[oti];
                int o = (4 * wv + oti) * 16 + lane15;
                if (wv < 2) {
                    xji[eg * 128 + o] = silu_f(v);
                } else {
                    float rh = rb[0] * wr[oti][0] + rb[1] * wr[oti][1] + rb[2] * wr[oti][2]
                             + rb[3] * wr[oti][3] + rb[4] * wr[oti][4] + rb[5] * wr[oti][5];
                    xkj[eg * 128 + (o - 128)] = silu_f(v) * rh;
                }
            }
        }
}

// ---- K4: fused  P-build -> MFMA agg GEMM -> +x_ji -> MFMA final linear -> silu ----
// 16 edges/block, 256 threads. LDS: 64KB split-bf16 P planes (XOR-swizzled), ~68KB total.
// No barriers inside either K-loop (B-frags come packed from global/L2).
__global__ __launch_bounds__(256, 2) void k_fused(
        const int* __restrict__ idx_kj,
        const float* __restrict__ xkj, const float* __restrict__ xji,
        const float* __restrict__ sbfb,
        const int* __restrict__ counts, const int* __restrict__ table,
        const unsigned short* __restrict__ wbh, const unsigned short* __restrict__ wbl,
        const unsigned short* __restrict__ wlh, const unsigned short* __restrict__ wll,
        const float* __restrict__ blin,
        float* __restrict__ hout) {
    __shared__ __align__(16) char sm[65536];   // P hi[16][1024] bf16 (32KB) + lo (32KB); reused
    __shared__ int s_cnt[16];
    __shared__ int s_row[16 * CAP];
    __shared__ int s_wid[16 * CAP];
    int tid = threadIdx.x;
    int e0 = blockIdx.x * 16;

    if (tid < 16) {
        int c = counts[e0 + tid];
        s_cnt[tid] = (c > CAP) ? CAP : c;
    }
    __syncthreads();
    for (int s = tid; s < 16 * CAP; s += 256) {
        int m = s >> 5, it = s & 31;
        if (it < s_cnt[m]) {
            int w = table[(e0 + m) * CAP + it];
            s_wid[s] = w;
            s_row[s] = idx_kj[w];
        }
    }
    __syncthreads();

    // phase 1b: P accumulation in fp32 registers. thread owns l = tid&127, j = j0+2c
    int l = tid & 127;
    int j0 = tid >> 7;
    int cnt_r[16];
    int maxc = 0;
#pragma unroll
    for (int m = 0; m < 16; ++m) {
        cnt_r[m] = s_cnt[m];
        maxc = max(maxc, cnt_r[m]);
    }
    float4 acc16[16];
#pragma unroll
    for (int m = 0; m < 16; ++m) acc16[m] = make_float4(0.f, 0.f, 0.f, 0.f);
    for (int it = 0; it < maxc; ++it) {
#pragma unroll
        for (int m = 0; m < 16; ++m) {
            if (it < cnt_r[m]) {
                int rw = s_row[m * CAP + it];
                int w = s_wid[m * CAP + it];
                float xv = xkj[(size_t)rw * 128 + l];
                const float4* sp = (const float4*)(sbfb + (size_t)w * 8);
                float4 sa = sp[0], sb = sp[1];
                float s0 = j0 ? sa.y : sa.x;
                float s1 = j0 ? sa.w : sa.z;
                float s2 = j0 ? sb.y : sb.x;
                float s3 = j0 ? sb.w : sb.z;
                acc16[m].x += s0 * xv;
                acc16[m].y += s1 * xv;
                acc16[m].z += s2 * xv;
                acc16[m].w += s3 * xv;
            }
        }
    }
    // write split-bf16 P planes, XOR-swizzled: byte = row*2048 + ((2k) ^ (row<<4))
    {
        char* sPh = sm;
        char* sPl = sm + 32768;
#pragma unroll
        for (int m = 0; m < 16; ++m) {
#pragma unroll
            for (int c = 0; c < 4; ++c) {
                float v = (c == 0) ? acc16[m].x : (c == 1) ? acc16[m].y
                        : (c == 2) ? acc16[m].z : acc16[m].w;
                int k = j0 * 128 + c * 256 + l;
                int off = m * 2048 + ((2 * k) ^ (m << 4));
                unsigned short hb, lb;
                split_bf16(v, hb, lb);
                *(unsigned short*)(sPh + off) = hb;
                *(unsigned short*)(sPl + off) = lb;
            }
        }
    }
    __syncthreads();

    // phase 2: agg[16,128] = P[16,1024] @ Wbil_k[1024,128] via split-bf16 MFMA.
    // wave wv owns i-tiles {2wv, 2wv+1}; A-frag: row=lane&15, k=(lane>>4)*8+e.
    int lane = tid & 63, wv = tid >> 6;
    int lane15 = lane & 15, laneh = lane >> 4;
    const char* sPh = sm;
    const char* sPl = sm + 32768;
    const bf16x8* BH = (const bf16x8*)wbh;
    const bf16x8* BL = (const bf16x8*)wbl;
    f32x4 a0 = {0.f, 0.f, 0.f, 0.f}, a1 = {0.f, 0.f, 0.f, 0.f};
#pragma unroll 4
    for (int s = 0; s < 32; ++s) {
        int koff = ((s * 32 + laneh * 8) * 2) ^ (lane15 << 4);
        bf16x8 ah = *(const bf16x8*)(sPh + lane15 * 2048 + koff);
        bf16x8 al = *(const bf16x8*)(sPl + lane15 * 2048 + koff);
        int b0 = ((2 * wv) * 32 + s) * 64 + lane;
        int b1 = b0 + 32 * 64;
        bf16x8 bh0 = BH[b0], bl0 = BL[b0];
        bf16x8 bh1 = BH[b1], bl1 = BL[b1];
        a0 = MFMA(ah, bh0, a0);
        a0 = MFMA(al, bh0, a0);
        a0 = MFMA(ah, bl0, a0);
        a1 = MFMA(ah, bh1, a1);
        a1 = MFMA(al, bh1, a1);
        a1 = MFMA(ah, bl1, a1);
    }
    __syncthreads();   // all P-plane reads done; reuse sm for y planes

    // y = agg + x_ji, split to bf16 planes [16][128] (4KB hi + 4KB lo), same swizzle
    {
        char* yh = sm;
        char* yl = sm + 4096;
#pragma unroll
        for (int it2 = 0; it2 < 2; ++it2) {
            int gi = (2 * wv + it2) * 16 + lane15;
            f32x4 av = it2 ? a1 : a0;
#pragma unroll
            for (int r = 0; r < 4; ++r) {
                int m2 = laneh * 4 + r;
                float yv = av[r] + xji[(size_t)(e0 + m2) * 128 + gi];
                int off = m2 * 256 + ((2 * gi) ^ (m2 << 4));
                unsigned short hb, lb;
                split_bf16(yv, hb, lb);
                *(unsigned short*)(yh + off) = hb;
                *(unsigned short*)(yl + off) = lb;
            }
        }
    }
    __syncthreads();

    // phase 3: h = silu(y[16,128] @ Wlin_k[128,128] + b) via split-bf16 MFMA
    const char* yh = sm;
    const char* yl = sm + 4096;
    const bf16x8* LH = (const bf16x8*)wlh;
    const bf16x8* LL = (const bf16x8*)wll;
    f32x4 c0 = {0.f, 0.f, 0.f, 0.f}, c1 = {0.f, 0.f, 0.f, 0.f};
#pragma unroll
    for (int s = 0; s < 4; ++s) {
        int koff = ((s * 32 + laneh * 8) * 2) ^ (lane15 << 4);
        bf16x8 ah = *(const bf16x8*)(yh + lane15 * 256 + koff);
        bf16x8 al = *(const bf16x8*)(yl + lane15 * 256 + koff);
        int b0 = ((2 * wv) * 4 + s) * 64 + lane;
        int b1 = b0 + 4 * 64;
        bf16x8 bh0 = LH[b0], bl0 = LL[b0];
        bf16x8 bh1 = LH[b1], bl1 = LL[b1];
        c0 = MFMA(ah, bh0, c0);
        c0 = MFMA(al, bh0, c0);
        c0 = MFMA(ah, bl0, c0);
        c1 = MFMA(ah, bh1, c1);
        c1 = MFMA(al, bh1, c1);
        c1 = MFMA(ah, bl1, c1);
    }
    __syncthreads();   // y-plane reads done; reuse sm as fp32 h-buffer

    float* hbuf = (float*)sm;   // [16][128] fp32 = 8KB
#pragma unroll
    for (int it2 = 0; it2 < 2; ++it2) {
        int o = (2 * wv + it2) * 16 + lane15;
        f32x4 cv = it2 ? c1 : c0;
#pragma unroll
        for (int r = 0; r < 4; ++r) {
            int m2 = laneh * 4 + r;
            hbuf[m2 * 128 + o] = silu_f(cv[r] + blin[o]);
        }
    }
    __syncthreads();
    int row = tid >> 4, colb = (tid & 15) * 8;
    float4 q0 = *(float4*)&hbuf[row * 128 + colb];
    float4 q1 = *(float4*)&hbuf[row * 128 + colb + 4];
    *(float4*)&hout[(size_t)(e0 + row) * 128 + colb] = q0;
    *(float4*)&hout[(size_t)(e0 + row) * 128 + colb + 4] = q1;
}

extern "C" void kernel_launch(void* const* d_in, const int* in_sizes, int n_in,
                              void* d_out, int out_size, void* d_ws, size_t ws_size,
                              hipStream_t stream) {
    const float* x = (const float*)d_in[0];
    const float* rbf = (const float*)d_in[1];
    const float* sbf = (const float*)d_in[2];
    const int* idx_kj = (const int*)d_in[3];
    const int* idx_ji = (const int*)d_in[4];
    const float* Wrbf = (const float*)d_in[5];
    const float* Wsbf = (const float*)d_in[6];
    const float* Wkj = (const float*)d_in[7];
    const float* bkj = (const float*)d_in[8];
    const float* Wji = (const float*)d_in[9];
    const float* bji = (const float*)d_in[10];
    const float* Wbil = (const float*)d_in[11];
    const float* Wlin = (const float*)d_in[12];
    const float* blin = (const float*)d_in[13];
    float* hout = (float*)d_out;

    char* ws = (char*)d_ws;
    float* xkj = (float*)(ws + O_XKJ);
    float* xji = (float*)(ws + O_XJI);
    float* sbfb = (float*)(ws + O_SBFB);
    unsigned short* wbh = (unsigned short*)(ws + O_WBH);
    unsigned short* wbl = (unsigned short*)(ws + O_WBL);
    unsigned short* wch = (unsigned short*)(ws + O_WCH);
    unsigned short* wcl = (unsigned short*)(ws + O_WCL);
    unsigned short* wlh = (unsigned short*)(ws + O_WLH);
    unsigned short* wll = (unsigned short*)(ws + O_WLL);
    int* cnts = (int*)(ws + O_CNT);
    int* tab = (int*)(ws + O_TAB);

    hipMemsetAsync(cnts, 0, (size_t)E_N * 4, stream);
    k_transpose<<<512, 256, 0, stream>>>(Wbil, Wji, Wkj, Wlin, wbh, wbl, wch, wcl, wlh, wll);
    k_build<<<(T_N + 255) / 256, 256, 0, stream>>>(idx_ji, cnts, tab);
    k_sbfb<<<(T_N + 255) / 256, 256, 0, stream>>>(sbf, Wsbf, sbfb);
    k_edges<<<E_N / 32, 256, 0, stream>>>(x, rbf, wch, wcl, Wrbf, bkj, bji, xkj, xji);
    k_fused<<<E_N / 16, 256, 0, stream>>>(idx_kj, xkj, xji, sbfb, cnts, tab,
                                          wbh, wbl, wlh, wll, blin, hout);
}

// Round 6
// 1746.409 us; speedup vs baseline: 3.3466x; 1.6625x over previous
//
#include <hip/hip_runtime.h>
#include <hip/hip_bf16.h>

#define E_N 300000
#define T_N 1500000
#define CAP 32   // triplet slots per edge; Poisson(mean 5) => P(overflow) ~ 1e-12

typedef __attribute__((ext_vector_type(8))) short bf16x8;
typedef __attribute__((ext_vector_type(4))) float f32x4;
#define MFMA(a, b, c) __builtin_amdgcn_mfma_f32_16x16x32_bf16((a), (b), (c), 0, 0, 0)

// ---- workspace layout (bytes); all offsets 16B-aligned ----
#define O_XKJ   ((size_t)0)
#define O_XJI   (O_XKJ + (size_t)E_N * 128 * 4)
#define O_SBFB  (O_XJI + (size_t)E_N * 128 * 4)
#define O_WBH   (O_SBFB + (size_t)T_N * 8 * 4)     // phase2 B hi: 8it*32s*64lane*8e bf16 = 256KB
#define O_WBL   (O_WBH + 262144)
#define O_WCH   (O_WBL + 262144)                   // k_edges B hi: 16ot*4s*64*8 = 64KB
#define O_WCL   (O_WCH + 65536)
#define O_WLH   (O_WCL + 65536)                    // phase3 B hi: 8ot*4s*64*8 = 32KB
#define O_WLL   (O_WLH + 32768)
#define O_CNT   (O_WLL + 32768)
#define O_TAB   (O_CNT + (size_t)E_N * 4)          // end ~395.5 MB

__device__ __forceinline__ float silu_f(float v) {
    return v / (1.0f + __expf(-v));
}

// split fp32 -> bf16 hi (truncate) + bf16 lo (residual, truncate). err <= 2^-16 rel.
__device__ __forceinline__ void split_bf16(float v, unsigned short& h, unsigned short& l) {
    unsigned int u = __float_as_uint(v);
    h = (unsigned short)(u >> 16);
    float vh = __uint_as_float(u & 0xffff0000u);
    l = (unsigned short)(__float_as_uint(v - vh) >> 16);
}

// ---- K0: pack all GEMM weights in MFMA B-fragment order, split hi/lo bf16 ----
// B-frag layout (16x16x32): lane provides B[k = (lane>>4)*8 + e][col = lane&15].
__global__ void k_transpose(const float* __restrict__ Wbil, const float* __restrict__ Wji,
                            const float* __restrict__ Wkj, const float* __restrict__ Wlin,
                            unsigned short* __restrict__ wbh, unsigned short* __restrict__ wbl,
                            unsigned short* __restrict__ wch, unsigned short* __restrict__ wcl,
                            unsigned short* __restrict__ wlh, unsigned short* __restrict__ wll) {
    int idx = blockIdx.x * 256 + threadIdx.x;   // 512*256 = 131072 exactly covers wbil
    {
        int e = idx & 7, ln = (idx >> 3) & 63, s = (idx >> 9) & 31, it = idx >> 14;
        int k = s * 32 + ((ln >> 4) << 3) + e;      // 0..1023 (= j*128+l)
        int i = it * 16 + (ln & 15);                // 0..127
        float w = Wbil[i * 1024 + k];
        split_bf16(w, wbh[idx], wbl[idx]);
    }
    if (idx < 32768) {
        int e = idx & 7, ln = (idx >> 3) & 63, s = (idx >> 9) & 3, ot = idx >> 11;
        int k = s * 32 + ((ln >> 4) << 3) + e;      // 0..127
        int o = ot * 16 + (ln & 15);                // 0..255
        float w = (o < 128) ? Wji[o * 128 + k] : Wkj[(o - 128) * 128 + k];
        split_bf16(w, wch[idx], wcl[idx]);
    }
    if (idx < 16384) {
        int e = idx & 7, ln = (idx >> 3) & 63, s = (idx >> 9) & 3, ot = (idx >> 11) & 7;
        int k = s * 32 + ((ln >> 4) << 3) + e;
        int o = ot * 16 + (ln & 15);
        float w = Wlin[o * 128 + k];
        split_bf16(w, wlh[idx], wll[idx]);
    }
}

// ---- K3: per-edge triplet table (counts zeroed by hipMemsetAsync before this) ----
__global__ void k_build(const int* __restrict__ idx_ji, int* __restrict__ counts,
                        int* __restrict__ table) {
    int w = blockIdx.x * 256 + threadIdx.x;
    if (w < T_N) {
        int e = idx_ji[w];
        int pos = atomicAdd(&counts[e], 1);
        if (pos < CAP) table[e * CAP + pos] = w;
    }
}

// ---- K1: sbf_b = sbf @ W_sbf.T  ([T,42] @ [42,8]) ----
__global__ __launch_bounds__(256) void k_sbfb(const float* __restrict__ sbf,
                                              const float* __restrict__ Wsbf,
                                              float* __restrict__ sbfb) {
    __shared__ float s_s[256 * 43];
    __shared__ float s_w[8 * 42];
    int tid = threadIdx.x;
    size_t t0 = (size_t)blockIdx.x * 256;
    int valid = T_N - (int)t0;
    if (valid > 256) valid = 256;
    for (int i = tid; i < 8 * 42; i += 256) s_w[i] = Wsbf[i];
    int tot = valid * 42;
    const float* src = sbf + t0 * 42;
    for (int i = tid; i < tot; i += 256) {
        int r = i / 42;
        int c = i - r * 42;
        s_s[r * 43 + c] = src[i];
    }
    __syncthreads();
    if (tid < valid) {
        float acc[8];
#pragma unroll
        for (int j = 0; j < 8; ++j) acc[j] = 0.f;
#pragma unroll 6
        for (int r = 0; r < 42; ++r) {
            float xv = s_s[tid * 43 + r];
#pragma unroll
            for (int j = 0; j < 8; ++j) acc[j] += xv * s_w[j * 42 + r];
        }
        float4* dst = (float4*)(sbfb + (t0 + tid) * 8);
        dst[0] = make_float4(acc[0], acc[1], acc[2], acc[3]);
        dst[1] = make_float4(acc[4], acc[5], acc[6], acc[7]);
    }
}

// ---- K2: fused edge linears via split-bf16 MFMA ----
__global__ __launch_bounds__(256, 2) void k_edges(const float* __restrict__ x,
                                                  const float* __restrict__ rbf,
                                                  const unsigned short* __restrict__ wch,
                                                  const unsigned short* __restrict__ wcl,
                                                  const float* __restrict__ Wrbf,
                                                  const float* __restrict__ bkj,
                                                  const float* __restrict__ bji,
                                                  float* __restrict__ xkj,
                                                  float* __restrict__ xji) {
    __shared__ float s_rbf[32 * 6];
    int tid = threadIdx.x;
    int lane = tid & 63, wv = tid >> 6, lane15 = lane & 15, laneh = lane >> 4;
    int e0 = blockIdx.x * 32;
    if (tid < 192) s_rbf[tid] = rbf[e0 * 6 + tid];
    __syncthreads();
    const bf16x8* WH = (const bf16x8*)wch;
    const bf16x8* WL = (const bf16x8*)wcl;
    f32x4 acc[2][4];
#pragma unroll
    for (int mt = 0; mt < 2; ++mt)
#pragma unroll
        for (int o = 0; o < 4; ++o) acc[mt][o] = (f32x4){0.f, 0.f, 0.f, 0.f};
#pragma unroll
    for (int s = 0; s < 4; ++s) {
        bf16x8 Ah[2], Al[2];
#pragma unroll
        for (int mt = 0; mt < 2; ++mt) {
            const float* px = &x[(size_t)(e0 + mt * 16 + lane15) * 128 + s * 32 + laneh * 8];
            float4 v0 = *(const float4*)px;
            float4 v1 = *(const float4*)(px + 4);
            float vv[8] = {v0.x, v0.y, v0.z, v0.w, v1.x, v1.y, v1.z, v1.w};
            union { bf16x8 v; unsigned short u[8]; } th, tl;
#pragma unroll
            for (int e = 0; e < 8; ++e) split_bf16(vv[e], th.u[e], tl.u[e]);
            Ah[mt] = th.v;
            Al[mt] = tl.v;
        }
#pragma unroll
        for (int oti = 0; oti < 4; ++oti) {
            int bi = ((4 * wv + oti) * 4 + s) * 64 + lane;
            bf16x8 bh = WH[bi], bl = WL[bi];
#pragma unroll
            for (int mt = 0; mt < 2; ++mt) {
                acc[mt][oti] = MFMA(Ah[mt], bh, acc[mt][oti]);
                acc[mt][oti] = MFMA(Al[mt], bh, acc[mt][oti]);
                acc[mt][oti] = MFMA(Ah[mt], bl, acc[mt][oti]);
            }
        }
    }
    float bias[4], wr[4][6];
#pragma unroll
    for (int oti = 0; oti < 4; ++oti) {
        int o = (4 * wv + oti) * 16 + lane15;
        if (wv < 2) {
            bias[oti] = bji[o];
        } else {
            bias[oti] = bkj[o - 128];
#pragma unroll
            for (int q = 0; q < 6; ++q) wr[oti][q] = Wrbf[(o - 128) * 6 + q];
        }
    }
#pragma unroll
    for (int mt = 0; mt < 2; ++mt)
#pragma unroll
        for (int r = 0; r < 4; ++r) {
            int erow = mt * 16 + laneh * 4 + r;
            float rb[6];
            if (wv >= 2) {
#pragma unroll
                for (int q = 0; q < 6; ++q) rb[q] = s_rbf[erow * 6 + q];
            }
            size_t eg = (size_t)(e0 + erow);
#pragma unroll
            for (int oti = 0; oti < 4; ++oti) {
                float v = acc[mt][oti][r] + bias[oti];
                int o = (4 * wv + oti) * 16 + lane15;
                if (wv < 2) {
                    xji[eg * 128 + o] = silu_f(v);
                } else {
                    float rh = rb[0] * wr[oti][0] + rb[1] * wr[oti][1] + rb[2] * wr[oti][2]
                             + rb[3] * wr[oti][3] + rb[4] * wr[oti][4] + rb[5] * wr[oti][5];
                    xkj[eg * 128 + (o - 128)] = silu_f(v) * rh;
                }
            }
        }
}

// ---- K4: fused gather -> MFMA bilinear -> +x_ji -> MFMA final linear -> silu ----
// 32 edges/block, 512 threads (8 waves). Wave-per-edge gather: 4 independent
// pipelined chains/wave; w,rw wave-uniform -> scalar sbfb loads + coalesced rows.
// LDS: P planes [32][1024] bf16 hi+lo = 128KB (XOR-swizzled), 1 block/CU.
__global__ __launch_bounds__(512, 2) void k_fused(
        const int* __restrict__ idx_kj,
        const float* __restrict__ xkj, const float* __restrict__ xji,
        const float* __restrict__ sbfb,
        const int* __restrict__ counts, const int* __restrict__ table,
        const unsigned short* __restrict__ wbh, const unsigned short* __restrict__ wbl,
        const unsigned short* __restrict__ wlh, const unsigned short* __restrict__ wll,
        const float* __restrict__ blin,
        float* __restrict__ hout) {
    __shared__ __align__(16) char sm[131072];   // P hi [32][1024]bf16 @0, lo @65536; reused for y
    __shared__ int s_cnt[32];
    __shared__ int s_row[32 * CAP];
    __shared__ int s_wid[32 * CAP];
    int tid = threadIdx.x;
    int lane = tid & 63, wv = tid >> 6;
    int e0 = blockIdx.x * 32;

    if (tid < 32) {
        int c = counts[e0 + tid];
        s_cnt[tid] = (c > CAP) ? CAP : c;
    }
    __syncthreads();
    for (int s = tid; s < 32 * CAP; s += 512) {
        int m = s >> 5, it = s & 31;
        if (it < s_cnt[m]) {
            int w = table[(e0 + m) * CAP + it];
            s_wid[s] = w;
            s_row[s] = idx_kj[w];
        }
    }
    __syncthreads();

    char* sPh = sm;
    char* sPl = sm + 65536;

    // ---- gather: wave wv owns edges {wv, wv+8, wv+16, wv+24}; 4 pipelined chains ----
    {
        int m0 = wv, m1 = wv + 8, m2 = wv + 16, m3 = wv + 24;
        int c0 = __builtin_amdgcn_readfirstlane(s_cnt[m0]);
        int c1 = __builtin_amdgcn_readfirstlane(s_cnt[m1]);
        int c2 = __builtin_amdgcn_readfirstlane(s_cnt[m2]);
        int c3 = __builtin_amdgcn_readfirstlane(s_cnt[m3]);
        int mx = max(max(c0, c1), max(c2, c3));
        float acc0[8][2] = {}, acc1[8][2] = {}, acc2[8][2] = {}, acc3[8][2] = {};
        float2 x0, x1, x2, x3;
        float4 sa0, sb0, sa1, sb1, sa2, sb2, sa3, sb3;

#define GLOAD(Q, ITV)                                                              \
        if ((ITV) < c##Q) {                                                        \
            int w_ = __builtin_amdgcn_readfirstlane(s_wid[m##Q * CAP + (ITV)]);    \
            int r_ = __builtin_amdgcn_readfirstlane(s_row[m##Q * CAP + (ITV)]);    \
            x##Q = *(const float2*)&xkj[(size_t)r_ * 128 + 2 * lane];              \
            const float4* sp_ = (const float4*)(sbfb + (size_t)w_ * 8);            \
            sa##Q = sp_[0];                                                        \
            sb##Q = sp_[1];                                                        \
        }
#define GFMA(Q, ITV)                                                               \
        if ((ITV) < c##Q) {                                                        \
            float sj_[8] = {sa##Q.x, sa##Q.y, sa##Q.z, sa##Q.w,                    \
                            sb##Q.x, sb##Q.y, sb##Q.z, sb##Q.w};                   \
            _Pragma("unroll") for (int j = 0; j < 8; ++j) {                        \
                acc##Q[j][0] += sj_[j] * x##Q.x;                                   \
                acc##Q[j][1] += sj_[j] * x##Q.y;                                   \
            }                                                                      \
        }

        GLOAD(0, 0) GLOAD(1, 0) GLOAD(2, 0) GLOAD(3, 0)
        for (int it = 0; it < mx; ++it) {
            GFMA(0, it) GLOAD(0, it + 1)
            GFMA(1, it) GLOAD(1, it + 1)
            GFMA(2, it) GLOAD(2, it + 1)
            GFMA(3, it) GLOAD(3, it + 1)
        }
#undef GLOAD
#undef GFMA

        // write P rows: k = j*128 + 2*lane (+1); byte = m*2048 + ((2k) ^ (m<<4))
#define PWRITE(Q)                                                                  \
        {                                                                          \
            _Pragma("unroll") for (int j = 0; j < 8; ++j) {                        \
                unsigned short h0_, l0_, h1_, l1_;                                 \
                split_bf16(acc##Q[j][0], h0_, l0_);                                \
                split_bf16(acc##Q[j][1], h1_, l1_);                                \
                int off_ = m##Q * 2048 + ((j * 256 + 4 * lane) ^ (m##Q << 4));     \
                *(unsigned int*)(sPh + off_) = (unsigned int)h0_ | ((unsigned int)h1_ << 16); \
                *(unsigned int*)(sPl + off_) = (unsigned int)l0_ | ((unsigned int)l1_ << 16); \
            }                                                                      \
        }
        PWRITE(0) PWRITE(1) PWRITE(2) PWRITE(3)
#undef PWRITE
    }
    __syncthreads();

    // ---- phase 2: agg[32,128] = P @ Wbil_k[1024,128]; wave wv owns i-tile wv ----
    int lane15 = lane & 15, laneh = lane >> 4;
    const bf16x8* BH = (const bf16x8*)wbh;
    const bf16x8* BL = (const bf16x8*)wbl;
    f32x4 a0 = {0.f, 0.f, 0.f, 0.f}, a1 = {0.f, 0.f, 0.f, 0.f};
    int rA0 = lane15, rA1 = 16 + lane15;
    int swz0 = rA0 << 4, swz1 = rA1 << 4;
#pragma unroll 4
    for (int s = 0; s < 32; ++s) {
        int kb = (s * 32 + laneh * 8) * 2;
        bf16x8 ah0 = *(const bf16x8*)(sPh + rA0 * 2048 + (kb ^ swz0));
        bf16x8 al0 = *(const bf16x8*)(sPl + rA0 * 2048 + (kb ^ swz0));
        bf16x8 ah1 = *(const bf16x8*)(sPh + rA1 * 2048 + (kb ^ swz1));
        bf16x8 al1 = *(const bf16x8*)(sPl + rA1 * 2048 + (kb ^ swz1));
        int bi = (wv * 32 + s) * 64 + lane;
        bf16x8 bh = BH[bi], bl = BL[bi];
        a0 = MFMA(ah0, bh, a0);
        a0 = MFMA(al0, bh, a0);
        a0 = MFMA(ah0, bl, a0);
        a1 = MFMA(ah1, bh, a1);
        a1 = MFMA(al1, bh, a1);
        a1 = MFMA(ah1, bl, a1);
    }
    __syncthreads();   // all P reads done; reuse sm for y planes

    // ---- y = agg + x_ji -> split-bf16 planes [32][128] (8KB hi + 8KB lo) ----
    char* yh = sm;
    char* yl = sm + 8192;
    {
        int col = wv * 16 + lane15;
#pragma unroll
        for (int mt = 0; mt < 2; ++mt) {
            f32x4 av = mt ? a1 : a0;
#pragma unroll
            for (int r = 0; r < 4; ++r) {
                int row = mt * 16 + laneh * 4 + r;
                float yv = av[r] + xji[(size_t)(e0 + row) * 128 + col];
                unsigned short hb, lb;
                split_bf16(yv, hb, lb);
                int off = row * 256 + ((2 * col) ^ ((row & 15) << 4));
                *(unsigned short*)(yh + off) = hb;
                *(unsigned short*)(yl + off) = lb;
            }
        }
    }
    __syncthreads();

    // ---- phase 3: h = silu(y[32,128] @ Wlin_k[128,128] + b) ----
    const bf16x8* LH = (const bf16x8*)wlh;
    const bf16x8* LL = (const bf16x8*)wll;
    f32x4 q0 = {0.f, 0.f, 0.f, 0.f}, q1 = {0.f, 0.f, 0.f, 0.f};
#pragma unroll
    for (int s = 0; s < 4; ++s) {
        int kb = (s * 32 + laneh * 8) * 2;
        bf16x8 ah0 = *(const bf16x8*)(yh + rA0 * 256 + (kb ^ swz0));
        bf16x8 al0 = *(const bf16x8*)(yl + rA0 * 256 + (kb ^ swz0));
        bf16x8 ah1 = *(const bf16x8*)(yh + rA1 * 256 + (kb ^ ((rA1 & 15) << 4)));
        bf16x8 al1 = *(const bf16x8*)(yl + rA1 * 256 + (kb ^ ((rA1 & 15) << 4)));
        int bi = (wv * 4 + s) * 64 + lane;
        bf16x8 bh = LH[bi], bl = LL[bi];
        q0 = MFMA(ah0, bh, q0);
        q0 = MFMA(al0, bh, q0);
        q0 = MFMA(ah0, bl, q0);
        q1 = MFMA(ah1, bh, q1);
        q1 = MFMA(al1, bh, q1);
        q1 = MFMA(ah1, bl, q1);
    }
    {
        int col = wv * 16 + lane15;
        float bl_ = blin[col];
#pragma unroll
        for (int mt = 0; mt < 2; ++mt) {
            f32x4 cv = mt ? q1 : q0;
#pragma unroll
            for (int r = 0; r < 4; ++r) {
                int row = mt * 16 + laneh * 4 + r;
                hout[(size_t)(e0 + row) * 128 + col] = silu_f(cv[r] + bl_);
            }
        }
    }
}

extern "C" void kernel_launch(void* const* d_in, const int* in_sizes, int n_in,
                              void* d_out, int out_size, void* d_ws, size_t ws_size,
                              hipStream_t stream) {
    const float* x = (const float*)d_in[0];
    const float* rbf = (const float*)d_in[1];
    const float* sbf = (const float*)d_in[2];
    const int* idx_kj = (const int*)d_in[3];
    const int* idx_ji = (const int*)d_in[4];
    const float* Wrbf = (const float*)d_in[5];
    const float* Wsbf = (const float*)d_in[6];
    const float* Wkj = (const float*)d_in[7];
    const float* bkj = (const float*)d_in[8];
    const float* Wji = (const float*)d_in[9];
    const float* bji = (const float*)d_in[10];
    const float* Wbil = (const float*)d_in[11];
    const float* Wlin = (const float*)d_in[12];
    const float* blin = (const float*)d_in[13];
    float* hout = (float*)d_out;

    char* ws = (char*)d_ws;
    float* xkj = (float*)(ws + O_XKJ);
    float* xji = (float*)(ws + O_XJI);
    float* sbfb = (float*)(ws + O_SBFB);
    unsigned short* wbh = (unsigned short*)(ws + O_WBH);
    unsigned short* wbl = (unsigned short*)(ws + O_WBL);
    unsigned short* wch = (unsigned short*)(ws + O_WCH);
    unsigned short* wcl = (unsigned short*)(ws + O_WCL);
    unsigned short* wlh = (unsigned short*)(ws + O_WLH);
    unsigned short* wll = (unsigned short*)(ws + O_WLL);
    int* cnts = (int*)(ws + O_CNT);
    int* tab = (int*)(ws + O_TAB);

    hipMemsetAsync(cnts, 0, (size_t)E_N * 4, stream);
    k_transpose<<<512, 256, 0, stream>>>(Wbil, Wji, Wkj, Wlin, wbh, wbl, wch, wcl, wlh, wll);
    k_build<<<(T_N + 255) / 256, 256, 0, stream>>>(idx_ji, cnts, tab);
    k_sbfb<<<(T_N + 255) / 256, 256, 0, stream>>>(sbf, Wsbf, sbfb);
    k_edges<<<E_N / 32, 256, 0, stream>>>(x, rbf, wch, wcl, Wrbf, bkj, bji, xkj, xji);
    k_fused<<<E_N / 32, 512, 0, stream>>>(idx_kj, xkj, xji, sbfb, cnts, tab,
                                          wbh, wbl, wlh, wll, blin, hout);
}